// Round 19
// baseline (249.392 us; speedup 1.0000x reference)
//
#include <hip/hip_runtime.h>
#include <stdint.h>

typedef float  f32x4  __attribute__((ext_vector_type(4)));
typedef __bf16 bf16x8 __attribute__((ext_vector_type(8)));

#define AS1 __attribute__((address_space(1)))
#define AS3 __attribute__((address_space(3)))

// Problem constants: B=2, S=2048, HID=2048, NH=16, HD=128, RING=4, CH=512, DIL=2
// packed length per (b,h,parity) = 1024; packed kv-chunk = 256
// BLOCKED operand layout (both GEMMs): elem(r, k) at
//   ((k>>5)*RB + (r>>7))*4096 + ((k>>3)&3)*1024 + (r&127)*8 + (k&7)
// RB = number of 128-row blocks. A wave's fragment = contiguous 1KB run.

// ---------------- fused conversion kernel (3 regions, 1 launch) ----------------
__global__ void k_cvt_all(const float* __restrict__ x, __bf16* __restrict__ xb,
                          const float* __restrict__ wqkv, __bf16* __restrict__ wqkvb,
                          const float* __restrict__ wout, __bf16* __restrict__ woutb) {
  __shared__ float tile[64][65];
  const int bx = blockIdx.x, t = threadIdx.x;
  if (bx < 4096) {
    const int d = bx * 256 + t;
    const int row = d & 127, kg = (d >> 7) & 3, mbkt = d >> 9;
    const int mb = mbkt & 31, kt = mbkt >> 5;
    const int m = mb * 128 + row, k0 = kt * 32 + kg * 8;
    const float4 v0 = *reinterpret_cast<const float4*>(x + (size_t)m * 2048 + k0);
    const float4 v1 = *reinterpret_cast<const float4*>(x + (size_t)m * 2048 + k0 + 4);
    bf16x8 o;
    o[0] = (__bf16)v0.x; o[1] = (__bf16)v0.y; o[2] = (__bf16)v0.z; o[3] = (__bf16)v0.w;
    o[4] = (__bf16)v1.x; o[5] = (__bf16)v1.y; o[6] = (__bf16)v1.z; o[7] = (__bf16)v1.w;
    *reinterpret_cast<bf16x8*>(xb + (size_t)d * 8) = o;
    return;
  }
  const float* w; __bf16* wt; int N, NBK, i0;
  if (bx < 7168) { w = wqkv; wt = wqkvb; N = 6144; NBK = 48; i0 = bx - 4096; }
  else           { w = wout; wt = woutb; N = 2048; NBK = 16; i0 = bx - 7168; }
  const int k0 = (i0 & 31) * 64, n0 = (i0 >> 5) * 64;
  #pragma unroll
  for (int i = 0; i < 16; ++i) {
    const int idx = t + 256 * i;
    const int r = idx >> 6, c = idx & 63;
    tile[r][c] = w[(size_t)(k0 + r) * N + n0 + c];
  }
  __syncthreads();
  #pragma unroll
  for (int i = 0; i < 2; ++i) {
    const int v = t + 256 * i;
    const int kb = v >> 6, nn = v & 63;
    const int n = n0 + nn, k = k0 + kb * 8;
    bf16x8 o;
    #pragma unroll
    for (int j = 0; j < 8; ++j) o[j] = (__bf16)tile[kb * 8 + j][nn];
    const size_t dst = ((size_t)(k >> 5) * NBK + (n >> 7)) * 4096 +
                       (size_t)((k >> 3) & 3) * 1024 + (n & 127) * 8;
    *reinterpret_cast<bf16x8*>(wt + dst) = o;
  }
}

// ---------------- pipelined blocked GEMM v10: A via LDS, B via L2 registers --------
// r18 counters: LDS-port-bound (18MB/CU LDS traffic ~ 88us vs 41us MFMA).
// Change: B fragments read DIRECTLY from global (L2-resident nb-strip; blocked
// layout makes a wave's fragment a contiguous 1KB run) into a register
// ping-pong (bcur/bnxt, named arrays), prefetched one K-step ahead. LDS now
// carries only A -> traffic halved. A path byte-identical to r8 (tri-buffer,
// dist-2, same-iteration ds_read consumption -> WAR invariant intact).
// vmcnt ledger: per iter issues A-stage(t+2)=2 then B(t+1)=4 (in-order VMEM).
// MFMA's auto-wait on B(t) retires the older A(t+1); explicit vmcnt(6) kept
// as a deterministic floor. Tail: t>=62 drains to vmcnt(0).
template<int NBB, int STRIP, int EPI>
__global__ __launch_bounds__(256, 3) void k_gemm_v10(
    const __bf16* __restrict__ Ab, const __bf16* __restrict__ Bb,
    __bf16* __restrict__ Oq, __bf16* __restrict__ Ok, __bf16* __restrict__ Ov,
    float* __restrict__ Of) {
  __shared__ __bf16 SU[6][4096];   // [0..2]=A tri-buf; [3..5] free (epilogue T)
  const int tid = threadIdx.x;
  const int w = tid >> 6, l = tid & 63, g = l >> 4, l15 = l & 15;
  const int wr = w >> 1, wc = w & 1;
  const int bx = blockIdx.x;
  const int xcd = bx & 7, win = bx >> 3;
  const int nb = xcd * STRIP + win % STRIP;   // B strip L2-resident per XCD
  const int mb = win / STRIP;
  const size_t Abase = (size_t)mb * 4096, Bbase = (size_t)nb * 4096;
  const size_t Astep = (size_t)32 * 4096, Bstep = (size_t)NBB * 4096;
  const int soff = w * 1024;
  const int bfo = g * 1024 + (wc * 64 + l15) * 8;   // B frag offset within tile

  f32x4 acc[4][4] = {};

  auto STAGE_A = [&](int t, int b) {
    const __bf16* as_ = Ab + (size_t)t * Astep + Abase + soff + l * 8;
    __builtin_amdgcn_global_load_lds((const AS1 uint32_t*)as_,
                                     (AS3 uint32_t*)(&SU[b][soff]), 16, 0, 0);
    __builtin_amdgcn_global_load_lds((const AS1 uint32_t*)(as_ + 512),
                                     (AS3 uint32_t*)(&SU[b][soff + 512]), 16, 0, 0);
  };
  auto LOADB = [&](bf16x8 (&fb)[4], int t) {
    const __bf16* bp = Bb + (size_t)t * Bstep + Bbase + bfo;
    #pragma unroll
    for (int ni = 0; ni < 4; ++ni)
      fb[ni] = *reinterpret_cast<const bf16x8*>(bp + ni * 128);
  };

  bf16x8 bA[4], bB[4];

  // prologue: A tiles 0,1 in flight; B(0) in regs; retire A(0) (vmcnt(6):
  // outstanding = A(1)=2 + B(0)=4 after wait).
  STAGE_A(0, 0);
  STAGE_A(1, 1);
  LOADB(bA, 0);
  asm volatile("s_waitcnt vmcnt(6)" ::: "memory");
  __builtin_amdgcn_s_barrier();

  auto body = [&](int t, int cur, bf16x8 (&bcur)[4], bf16x8 (&bnxt)[4]) {
    int b2 = cur + 2; if (b2 >= 3) b2 -= 3;
    if (t + 2 < 64) STAGE_A(t + 2, b2);
    if (t + 1 < 64) LOADB(bnxt, t + 1);
    const __bf16* Ar = &SU[cur][g * 1024 + (wr * 64 + l15) * 8];
    bf16x8 af[4];
    #pragma unroll
    for (int mi = 0; mi < 4; ++mi) af[mi] = *reinterpret_cast<const bf16x8*>(Ar + mi * 128);
    __builtin_amdgcn_s_setprio(1);
    #pragma unroll
    for (int mi = 0; mi < 4; ++mi)
      #pragma unroll
      for (int ni = 0; ni < 4; ++ni)
        acc[mi][ni] = __builtin_amdgcn_mfma_f32_16x16x32_bf16(af[mi], bcur[ni], acc[mi][ni], 0, 0, 0);
    __builtin_amdgcn_s_setprio(0);
    __builtin_amdgcn_sched_barrier(0);
    if (t < 62) asm volatile("s_waitcnt vmcnt(6)" ::: "memory");  // A(t+1) retired
    else        asm volatile("s_waitcnt vmcnt(0)" ::: "memory");  // tail drain
    __builtin_amdgcn_s_barrier();
  };

  int cur = 0;
  for (int tt = 0; tt < 32; ++tt) {
    body(2 * tt, cur, bA, bB);
    cur = cur + 1; if (cur >= 3) cur -= 3;
    body(2 * tt + 1, cur, bB, bA);
    cur = cur + 1; if (cur >= 3) cur -= 3;
  }

  if constexpr (EPI == 1) {
    const int m0 = mb * 128, n0 = nb * 128;
    const int ty = n0 >> 11;                // 0:q 1:k 2:v (block-uniform)
    const int h = (n0 & 2047) >> 7;
    if (ty != 2) {
      #pragma unroll
      for (int mi = 0; mi < 4; ++mi) {
        #pragma unroll
        for (int r = 0; r < 4; ++r) {
          const int m = m0 + wr * 64 + mi * 16 + 4 * g + r;
          const int s = m & 2047;
          const int sp = s & 1, s2 = s >> 1;
          const int bb = m >> 11;
          const size_t base = ((((size_t)bb * 16 + h) * 2 + sp) << 17);
          #pragma unroll
          for (int ni = 0; ni < 4; ++ni) {
            const int d = wc * 64 + ni * 16 + l15;
            const __bf16 v = (__bf16)acc[mi][ni][r];
            if (ty == 0) Oq[base + (size_t)s2 * 128 + d] = v;
            else         Ok[base + (size_t)s2 * 128 + d] = v;
          }
        }
      }
    } else {
      // V: transpose via LDS (staging dead), then dense b128 stores along s2.
      __bf16* T = &SU[0][0];                // [128][136] tile, 34816B < 48KB
      #pragma unroll
      for (int mi = 0; mi < 4; ++mi)
        #pragma unroll
        for (int r = 0; r < 4; ++r)
          #pragma unroll
          for (int ni = 0; ni < 4; ++ni)
            T[(size_t)(wr * 64 + mi * 16 + 4 * g + r) * 136 + wc * 64 + ni * 16 + l15] =
                (__bf16)acc[mi][ni][r];
      __syncthreads();
      const int d = tid >> 1, sp = tid & 1;
      const int bb = m0 >> 11;
      const size_t vbase = ((((size_t)bb * 16 + h) * 2 + sp) << 17) +
                           (size_t)d * 1024 + ((m0 & 2047) >> 1);
      #pragma unroll
      for (int j = 0; j < 8; ++j) {
        bf16x8 o;
        #pragma unroll
        for (int q = 0; q < 8; ++q)
          o[q] = T[(size_t)(16 * j + 2 * q + sp) * 136 + d];
        *reinterpret_cast<bf16x8*>(Ov + vbase + 8 * j) = o;
      }
    }
  } else {
    #pragma unroll
    for (int mi = 0; mi < 4; ++mi)
      #pragma unroll
      for (int r = 0; r < 4; ++r) {
        const int m = mb * 128 + wr * 64 + mi * 16 + 4 * g + r;
        #pragma unroll
        for (int ni = 0; ni < 4; ++ni) {
          const int n = nb * 128 + wc * 64 + ni * 16 + l15;
          Of[(size_t)m * 2048 + n] = acc[mi][ni][r];
        }
      }
  }
}

// ---------------- fused dilated ring attention v5 (r15-18 verbatim) ----------------
__global__ __launch_bounds__(256, 2) void k_attn(
    const __bf16* __restrict__ Qp, const __bf16* __restrict__ Kp,
    const __bf16* __restrict__ Vt, __bf16* __restrict__ attnA) {
  __shared__ __bf16 U[3][8192];     // union K/V staging tri-buffer (48 KB)
  __shared__ __bf16 E[4][16][136];  // wave-private exp tiles (17 KB)

  const int bx = blockIdx.x;
  const int wid = (bx & 7) * 128 + (bx >> 3);
  const int qt = wid & 15, pp = (wid >> 4) & 1, h = (wid >> 5) & 15, b = wid >> 9;
  const int tid = threadIdx.x;
  const int w = tid >> 6, l = tid & 63, g = l >> 4, l15 = l & 15;
  const size_t base = ((((size_t)b * 16 + h) * 2 + pp) << 17);
  const __bf16* Qb = Qp + base;
  const __bf16* Kb = Kp + base;
  const __bf16* Vb = Vt + base;
  const int q0 = qt * 64 + w * 16;
  const float SC = 1.4426950408889634f / 11.313708498984761f;  // log2(e)/sqrt(128)

  const int krow_in = l >> 4;
  const int vrow_in = l >> 3;
  const int vsrc_e = (((l & 7) * 16) ^ (vrow_in << 4)) >> 1;

  bf16x8 qf[4];
  #pragma unroll
  for (int ks = 0; ks < 4; ++ks)
    qf[ks] = *reinterpret_cast<const bf16x8*>(Qb + (size_t)(q0 + l15) * 128 + ks * 32 + 8 * g);

  f32x4 num[8] = {};
  float den[4] = {0.f, 0.f, 0.f, 0.f};
  f32x4 s[16];

  auto STAGE = [&](int p) {
    const int c = p >> 3, j = p & 7, bi = p % 3;
    if (j < 4) {
      #pragma unroll
      for (int i = 0; i < 4; ++i) {
        const int ch = w * 4 + i;
        const int row = ch * 4 + krow_in;
        const int cb = (l15 * 16) ^ ((row & 7) << 4);
        const __bf16* src = Kb + (size_t)(c * 256 + j * 64 + row) * 128 + (cb >> 1);
        __builtin_amdgcn_global_load_lds((const AS1 uint32_t*)src,
                                         (AS3 uint32_t*)(&U[bi][ch * 512]), 16, 0, 0);
      }
    } else {
      const int kv0 = c * 256 + ((j - 4) >> 1) * 128 + ((j - 4) & 1) * 64;
      #pragma unroll
      for (int i = 0; i < 4; ++i) {
        const int ch = w * 4 + i;
        const int row = ch * 8 + vrow_in;
        const __bf16* src = Vb + (size_t)row * 1024 + kv0 + vsrc_e;
        __builtin_amdgcn_global_load_lds((const AS1 uint32_t*)src,
                                         (AS3 uint32_t*)(&U[bi][ch * 512]), 16, 0, 0);
      }
    }
  };
  auto ENDPHASE = [&](int p) {
    if (p <= 29)      asm volatile("s_waitcnt vmcnt(4)" ::: "memory");
    else if (p == 30) asm volatile("s_waitcnt vmcnt(0)" ::: "memory");
    if (p < 31) __builtin_amdgcn_s_barrier();
  };

  STAGE(0);
  STAGE(1);
  asm volatile("s_waitcnt vmcnt(4)" ::: "memory");
  __builtin_amdgcn_s_barrier();

  for (int c = 0; c < 4; ++c) {
    const int pb = 8 * c;
    #pragma unroll
    for (int i = 0; i < 16; ++i) s[i] = f32x4{0.f, 0.f, 0.f, 0.f};
    #pragma unroll
    for (int st = 0; st < 4; ++st) {
      const int p = pb + st;
      if (p + 2 < 32) STAGE(p + 2);
      const __bf16* Kbuf = U[p % 3];
      __builtin_amdgcn_s_setprio(1);
      #pragma unroll
      for (int ks = 0; ks < 4; ++ks) {
        #pragma unroll
        for (int nf2 = 0; nf2 < 4; ++nf2) {
          const int r = nf2 * 16 + l15;
          const int cb = (ks * 64 + g * 16) ^ ((r & 7) << 4);
          const bf16x8 kf = *reinterpret_cast<const bf16x8*>(Kbuf + r * 128 + (cb >> 1));
          s[st * 4 + nf2] = __builtin_amdgcn_mfma_f32_16x16x32_bf16(qf[ks], kf, s[st * 4 + nf2], 0, 0, 0);
        }
      }
      __builtin_amdgcn_s_setprio(0);
      __builtin_amdgcn_sched_barrier(0);
      ENDPHASE(p);
    }
    float mv[4];
    #pragma unroll
    for (int r = 0; r < 4; ++r) {
      float m0v = s[0][r];
      #pragma unroll
      for (int nf = 1; nf < 16; ++nf) m0v = fmaxf(m0v, s[nf][r]);
      m0v = fmaxf(m0v, __shfl_xor(m0v, 1));
      m0v = fmaxf(m0v, __shfl_xor(m0v, 2));
      m0v = fmaxf(m0v, __shfl_xor(m0v, 4));
      m0v = fmaxf(m0v, __shfl_xor(m0v, 8));
      mv[r] = m0v;
    }
    #pragma unroll
    for (int r = 0; r < 4; ++r) {
      float ds = 0.f;
      #pragma unroll
      for (int nf = 0; nf < 16; ++nf) {
        const float e = exp2f((s[nf][r] - mv[r]) * SC);
        s[nf][r] = e;
        ds += e;
      }
      den[r] += ds;
    }
    #pragma unroll
    for (int h2 = 0; h2 < 2; ++h2) {
      #pragma unroll
      for (int nf = 0; nf < 8; ++nf)
        #pragma unroll
        for (int r = 0; r < 4; ++r)
          E[w][4 * g + r][nf * 16 + l15] = (__bf16)s[h2 * 8 + nf][r];
      #pragma unroll
      for (int sv = 0; sv < 2; ++sv) {
        const int p = pb + 4 + h2 * 2 + sv;
        if (p + 2 < 32) STAGE(p + 2);
        const __bf16* Vbuf = U[p % 3];
        __builtin_amdgcn_s_setprio(1);
        #pragma unroll
        for (int ks2 = 0; ks2 < 2; ++ks2) {
          const bf16x8 a = *reinterpret_cast<const bf16x8*>(
              &E[w][l15][sv * 64 + ks2 * 32 + 8 * g]);
          #pragma unroll
          for (int nd = 0; nd < 8; ++nd) {
            const int d = nd * 16 + l15;
            const int cb = (ks2 * 64 + g * 16) ^ ((d & 7) << 4);
            const bf16x8 vf = *reinterpret_cast<const bf16x8*>(Vbuf + d * 64 + (cb >> 1));
            num[nd] = __builtin_amdgcn_mfma_f32_16x16x32_bf16(a, vf, num[nd], 0, 0, 0);
          }
        }
        __builtin_amdgcn_s_setprio(0);
        __builtin_amdgcn_sched_barrier(0);
        ENDPHASE(p);
      }
    }
  }

  #pragma unroll
  for (int r = 0; r < 4; ++r) {
    den[r] += __shfl_xor(den[r], 1);
    den[r] += __shfl_xor(den[r], 2);
    den[r] += __shfl_xor(den[r], 4);
    den[r] += __shfl_xor(den[r], 8);
    den[r] += 1e-8f;
  }

  #pragma unroll
  for (int nd = 0; nd < 8; ++nd)
    #pragma unroll
    for (int r = 0; r < 4; ++r) {
      const int sq = q0 + 4 * g + r;
      const int srow = 2 * sq + pp;
      const int m = b * 2048 + srow;
      const int k = h * 128 + nd * 16 + l15;
      const size_t dst = ((size_t)(k >> 5) * 32 + (m >> 7)) * 4096 +
                         (size_t)((k >> 3) & 3) * 1024 + (m & 127) * 8 + (k & 7);
      attnA[dst] = (__bf16)(num[nd][r] / den[r]);
    }
}

extern "C" void kernel_launch(void* const* d_in, const int* in_sizes, int n_in,
                              void* d_out, int out_size, void* d_ws, size_t ws_size,
                              hipStream_t stream) {
  (void)in_sizes; (void)n_in; (void)out_size; (void)ws_size;
  const float* x    = (const float*)d_in[0];
  const float* wqkv = (const float*)d_in[1];
  const float* wout = (const float*)d_in[2];
  float* out = (float*)d_out;
  uint8_t* ws = (uint8_t*)d_ws;

  // workspace layout (bytes); total needed = 96 MB
  __bf16* xbf   = (__bf16*)(ws + 0);                    // 16 MB blocked A (GEMM1)
  __bf16* wqkvt = (__bf16*)(ws + (16ull << 20));        // 24 MB blocked B (GEMM1, RB=48)
  __bf16* woutt = (__bf16*)(ws + (40ull << 20));        //  8 MB blocked B (GEMM2, RB=16)
  __bf16* Qp    = (__bf16*)(ws + (48ull << 20));        // 16 MB [b][h][p][1024][128]
  __bf16* Kp    = (__bf16*)(ws + (64ull << 20));        // 16 MB [b][h][p][1024][128]
  __bf16* Vt    = (__bf16*)(ws + (80ull << 20));        // 16 MB [b][h][p][128][1024]
  __bf16* attnA = (__bf16*)(ws + 0);                    // 16 MB blocked A (GEMM2); reuse xbf

  // fused conversions: x-blk (4096) + wqkv-blk (3072) + wout-blk (1024)
  k_cvt_all<<<8192, 256, 0, stream>>>(x, xbf, wqkv, wqkvt, wout, woutt);
  // qkv projection: v10 (A via LDS, B via L2 regs), nb-strip 6/XCD
  k_gemm_v10<48, 6, 1><<<1536, 256, 0, stream>>>(xbf, wqkvt, Qp, Kp, Vt, nullptr);
  // fused dilated attention v5 (r8-pipelined; writes blocked A for GEMM2)
  k_attn<<<1024, 256, 0, stream>>>(Qp, Kp, Vt, attnA);
  // output projection: v10, nb-strip 2/XCD; grid 512
  k_gemm_v10<16, 2, 2><<<512, 256, 0, stream>>>(attnA, woutt, nullptr, nullptr, nullptr, out);
}

// Round 20
// 237.672 us; speedup vs baseline: 1.0493x; 1.0493x over previous
//
#include <hip/hip_runtime.h>
#include <stdint.h>

typedef float  f32x4  __attribute__((ext_vector_type(4)));
typedef __bf16 bf16x8 __attribute__((ext_vector_type(8)));

#define AS1 __attribute__((address_space(1)))
#define AS3 __attribute__((address_space(3)))

// Problem constants: B=2, S=2048, HID=2048, NH=16, HD=128, RING=4, CH=512, DIL=2
// packed length per (b,h,parity) = 1024; packed kv-chunk = 256
// BLOCKED operand layout (both GEMMs): elem(r, k) at
//   ((k>>5)*RB + (r>>7))*4096 + ((k>>3)&3)*1024 + (r&127)*8 + (k&7)
// RB = number of 128-row blocks. LDS staging is an identity copy.

// ---------------- fused conversion kernel (3 regions, 1 launch) ----------------
__global__ void k_cvt_all(const float* __restrict__ x, __bf16* __restrict__ xb,
                          const float* __restrict__ wqkv, __bf16* __restrict__ wqkvb,
                          const float* __restrict__ wout, __bf16* __restrict__ woutb) {
  __shared__ float tile[64][65];
  const int bx = blockIdx.x, t = threadIdx.x;
  if (bx < 4096) {
    const int d = bx * 256 + t;
    const int row = d & 127, kg = (d >> 7) & 3, mbkt = d >> 9;
    const int mb = mbkt & 31, kt = mbkt >> 5;
    const int m = mb * 128 + row, k0 = kt * 32 + kg * 8;
    const float4 v0 = *reinterpret_cast<const float4*>(x + (size_t)m * 2048 + k0);
    const float4 v1 = *reinterpret_cast<const float4*>(x + (size_t)m * 2048 + k0 + 4);
    bf16x8 o;
    o[0] = (__bf16)v0.x; o[1] = (__bf16)v0.y; o[2] = (__bf16)v0.z; o[3] = (__bf16)v0.w;
    o[4] = (__bf16)v1.x; o[5] = (__bf16)v1.y; o[6] = (__bf16)v1.z; o[7] = (__bf16)v1.w;
    *reinterpret_cast<bf16x8*>(xb + (size_t)d * 8) = o;
    return;
  }
  const float* w; __bf16* wt; int N, NBK, i0;
  if (bx < 7168) { w = wqkv; wt = wqkvb; N = 6144; NBK = 48; i0 = bx - 4096; }
  else           { w = wout; wt = woutb; N = 2048; NBK = 16; i0 = bx - 7168; }
  const int k0 = (i0 & 31) * 64, n0 = (i0 >> 5) * 64;
  #pragma unroll
  for (int i = 0; i < 16; ++i) {
    const int idx = t + 256 * i;
    const int r = idx >> 6, c = idx & 63;
    tile[r][c] = w[(size_t)(k0 + r) * N + n0 + c];
  }
  __syncthreads();
  #pragma unroll
  for (int i = 0; i < 2; ++i) {
    const int v = t + 256 * i;
    const int kb = v >> 6, nn = v & 63;
    const int n = n0 + nn, k = k0 + kb * 8;
    bf16x8 o;
    #pragma unroll
    for (int j = 0; j < 8; ++j) o[j] = (__bf16)tile[kb * 8 + j][nn];
    const size_t dst = ((size_t)(k >> 5) * NBK + (n >> 7)) * 4096 +
                       (size_t)((k >> 3) & 3) * 1024 + (n & 127) * 8;
    *reinterpret_cast<bf16x8*>(wt + dst) = o;
  }
}

// ---------------- pipelined blocked GEMM (r18 VERBATIM): C = A * B^T ----------------
// Best-measured config (GEMM1 105us, MfmaUtil 45%, FETCH 109MB). r19's
// B-via-L2-registers variant regressed (105->116; L2 latency on the MFMA
// critical path) -- reverted. Do not touch the loop.
// STRIP>0: nb-strip XCD mapping (B strip L2-resident, A streams via L3).
template<int NBB, int CHK, int STRIP, int EPI>
__global__ __launch_bounds__(256, 3) void k_gemm_r8(
    const __bf16* __restrict__ Ab, const __bf16* __restrict__ Bb,
    __bf16* __restrict__ Oq, __bf16* __restrict__ Ok, __bf16* __restrict__ Ov,
    float* __restrict__ Of) {
  __shared__ __bf16 SU[6][4096];   // [0..2]=A tri-buf, [3..5]=B tri-buf
  const int tid = threadIdx.x;
  const int w = tid >> 6, l = tid & 63, g = l >> 4, l15 = l & 15;
  const int wr = w >> 1, wc = w & 1;
  const int bx = blockIdx.x;
  int nb, mb;
  if constexpr (STRIP > 0) {
    const int xcd = bx & 7, win = bx >> 3;
    nb = xcd * STRIP + win % STRIP;
    mb = win / STRIP;
  } else {
    const int wid = (bx & 7) * CHK + (bx >> 3);
    nb = wid % NBB;
    mb = wid / NBB;
  }
  const size_t Abase = (size_t)mb * 4096, Bbase = (size_t)nb * 4096;
  const size_t Astep = (size_t)32 * 4096, Bstep = (size_t)NBB * 4096;
  const int soff = w * 1024;

  f32x4 acc[4][4] = {};

  auto STAGE = [&](int t, int b) {
    const __bf16* as_ = Ab + (size_t)t * Astep + Abase + soff + l * 8;
    const __bf16* bs_ = Bb + (size_t)t * Bstep + Bbase + soff + l * 8;
    __builtin_amdgcn_global_load_lds((const AS1 uint32_t*)as_,
                                     (AS3 uint32_t*)(&SU[b][soff]), 16, 0, 0);
    __builtin_amdgcn_global_load_lds((const AS1 uint32_t*)(as_ + 512),
                                     (AS3 uint32_t*)(&SU[b][soff + 512]), 16, 0, 0);
    __builtin_amdgcn_global_load_lds((const AS1 uint32_t*)bs_,
                                     (AS3 uint32_t*)(&SU[3 + b][soff]), 16, 0, 0);
    __builtin_amdgcn_global_load_lds((const AS1 uint32_t*)(bs_ + 512),
                                     (AS3 uint32_t*)(&SU[3 + b][soff + 512]), 16, 0, 0);
  };

  STAGE(0, 0);
  STAGE(1, 1);
  asm volatile("s_waitcnt vmcnt(4)" ::: "memory");
  __builtin_amdgcn_s_barrier();

  int cur = 0;
  for (int t = 0; t < 64; ++t) {
    int b2 = cur + 2; if (b2 >= 3) b2 -= 3;
    if (t + 2 < 64) STAGE(t + 2, b2);
    const __bf16* Ar = &SU[cur][g * 1024 + (wr * 64 + l15) * 8];
    const __bf16* Br = &SU[3 + cur][g * 1024 + (wc * 64 + l15) * 8];
    bf16x8 af[4], bfr[4];
    #pragma unroll
    for (int mi = 0; mi < 4; ++mi) af[mi] = *reinterpret_cast<const bf16x8*>(Ar + mi * 128);
    #pragma unroll
    for (int ni = 0; ni < 4; ++ni) bfr[ni] = *reinterpret_cast<const bf16x8*>(Br + ni * 128);
    __builtin_amdgcn_s_setprio(1);
    #pragma unroll
    for (int mi = 0; mi < 4; ++mi)
      #pragma unroll
      for (int ni = 0; ni < 4; ++ni)
        acc[mi][ni] = __builtin_amdgcn_mfma_f32_16x16x32_bf16(af[mi], bfr[ni], acc[mi][ni], 0, 0, 0);
    __builtin_amdgcn_s_setprio(0);
    __builtin_amdgcn_sched_barrier(0);
    if (t < 62) asm volatile("s_waitcnt vmcnt(4)" ::: "memory");
    else        asm volatile("s_waitcnt vmcnt(0)" ::: "memory");
    __builtin_amdgcn_s_barrier();
    cur = cur + 1; if (cur >= 3) cur -= 3;
  }

  if constexpr (EPI == 1) {
    const int m0 = mb * 128, n0 = nb * 128;
    const int ty = n0 >> 11;                // 0:q 1:k 2:v (block-uniform)
    const int h = (n0 & 2047) >> 7;
    if (ty != 2) {
      #pragma unroll
      for (int mi = 0; mi < 4; ++mi) {
        #pragma unroll
        for (int r = 0; r < 4; ++r) {
          const int m = m0 + wr * 64 + mi * 16 + 4 * g + r;
          const int s = m & 2047;
          const int sp = s & 1, s2 = s >> 1;
          const int bb = m >> 11;
          const size_t base = ((((size_t)bb * 16 + h) * 2 + sp) << 17);
          #pragma unroll
          for (int ni = 0; ni < 4; ++ni) {
            const int d = wc * 64 + ni * 16 + l15;
            const __bf16 v = (__bf16)acc[mi][ni][r];
            if (ty == 0) Oq[base + (size_t)s2 * 128 + d] = v;
            else         Ok[base + (size_t)s2 * 128 + d] = v;
          }
        }
      }
    } else {
      // V: transpose via dead staging LDS, then dense b128 stores along s2.
      __bf16* T = &SU[0][0];                // [128][136] tile, 34816B < 48KB
      #pragma unroll
      for (int mi = 0; mi < 4; ++mi)
        #pragma unroll
        for (int r = 0; r < 4; ++r)
          #pragma unroll
          for (int ni = 0; ni < 4; ++ni)
            T[(size_t)(wr * 64 + mi * 16 + 4 * g + r) * 136 + wc * 64 + ni * 16 + l15] =
                (__bf16)acc[mi][ni][r];
      __syncthreads();
      const int d = tid >> 1, sp = tid & 1;
      const int bb = m0 >> 11;
      const size_t vbase = ((((size_t)bb * 16 + h) * 2 + sp) << 17) +
                           (size_t)d * 1024 + ((m0 & 2047) >> 1);
      #pragma unroll
      for (int j = 0; j < 8; ++j) {
        bf16x8 o;
        #pragma unroll
        for (int q = 0; q < 8; ++q)
          o[q] = T[(size_t)(16 * j + 2 * q + sp) * 136 + d];
        *reinterpret_cast<bf16x8*>(Ov + vbase + 8 * j) = o;
      }
    }
  } else {
    #pragma unroll
    for (int mi = 0; mi < 4; ++mi)
      #pragma unroll
      for (int r = 0; r < 4; ++r) {
        const int m = mb * 128 + wr * 64 + mi * 16 + 4 * g + r;
        #pragma unroll
        for (int ni = 0; ni < 4; ++ni) {
          const int n = nb * 128 + wc * 64 + ni * 16 + l15;
          Of[(size_t)m * 2048 + n] = acc[mi][ni][r];
        }
      }
  }
}

// ---------------- fused dilated ring attention v5 (r15-18 verbatim) ----------------
__global__ __launch_bounds__(256, 2) void k_attn(
    const __bf16* __restrict__ Qp, const __bf16* __restrict__ Kp,
    const __bf16* __restrict__ Vt, __bf16* __restrict__ attnA) {
  __shared__ __bf16 U[3][8192];     // union K/V staging tri-buffer (48 KB)
  __shared__ __bf16 E[4][16][136];  // wave-private exp tiles (17 KB)

  const int bx = blockIdx.x;
  const int wid = (bx & 7) * 128 + (bx >> 3);
  const int qt = wid & 15, pp = (wid >> 4) & 1, h = (wid >> 5) & 15, b = wid >> 9;
  const int tid = threadIdx.x;
  const int w = tid >> 6, l = tid & 63, g = l >> 4, l15 = l & 15;
  const size_t base = ((((size_t)b * 16 + h) * 2 + pp) << 17);
  const __bf16* Qb = Qp + base;
  const __bf16* Kb = Kp + base;
  const __bf16* Vb = Vt + base;
  const int q0 = qt * 64 + w * 16;
  const float SC = 1.4426950408889634f / 11.313708498984761f;  // log2(e)/sqrt(128)

  const int krow_in = l >> 4;
  const int vrow_in = l >> 3;
  const int vsrc_e = (((l & 7) * 16) ^ (vrow_in << 4)) >> 1;

  bf16x8 qf[4];
  #pragma unroll
  for (int ks = 0; ks < 4; ++ks)
    qf[ks] = *reinterpret_cast<const bf16x8*>(Qb + (size_t)(q0 + l15) * 128 + ks * 32 + 8 * g);

  f32x4 num[8] = {};
  float den[4] = {0.f, 0.f, 0.f, 0.f};
  f32x4 s[16];

  auto STAGE = [&](int p) {
    const int c = p >> 3, j = p & 7, bi = p % 3;
    if (j < 4) {
      #pragma unroll
      for (int i = 0; i < 4; ++i) {
        const int ch = w * 4 + i;
        const int row = ch * 4 + krow_in;
        const int cb = (l15 * 16) ^ ((row & 7) << 4);
        const __bf16* src = Kb + (size_t)(c * 256 + j * 64 + row) * 128 + (cb >> 1);
        __builtin_amdgcn_global_load_lds((const AS1 uint32_t*)src,
                                         (AS3 uint32_t*)(&U[bi][ch * 512]), 16, 0, 0);
      }
    } else {
      const int kv0 = c * 256 + ((j - 4) >> 1) * 128 + ((j - 4) & 1) * 64;
      #pragma unroll
      for (int i = 0; i < 4; ++i) {
        const int ch = w * 4 + i;
        const int row = ch * 8 + vrow_in;
        const __bf16* src = Vb + (size_t)row * 1024 + kv0 + vsrc_e;
        __builtin_amdgcn_global_load_lds((const AS1 uint32_t*)src,
                                         (AS3 uint32_t*)(&U[bi][ch * 512]), 16, 0, 0);
      }
    }
  };
  auto ENDPHASE = [&](int p) {
    if (p <= 29)      asm volatile("s_waitcnt vmcnt(4)" ::: "memory");
    else if (p == 30) asm volatile("s_waitcnt vmcnt(0)" ::: "memory");
    if (p < 31) __builtin_amdgcn_s_barrier();
  };

  STAGE(0);
  STAGE(1);
  asm volatile("s_waitcnt vmcnt(4)" ::: "memory");
  __builtin_amdgcn_s_barrier();

  for (int c = 0; c < 4; ++c) {
    const int pb = 8 * c;
    #pragma unroll
    for (int i = 0; i < 16; ++i) s[i] = f32x4{0.f, 0.f, 0.f, 0.f};
    #pragma unroll
    for (int st = 0; st < 4; ++st) {
      const int p = pb + st;
      if (p + 2 < 32) STAGE(p + 2);
      const __bf16* Kbuf = U[p % 3];
      __builtin_amdgcn_s_setprio(1);
      #pragma unroll
      for (int ks = 0; ks < 4; ++ks) {
        #pragma unroll
        for (int nf2 = 0; nf2 < 4; ++nf2) {
          const int r = nf2 * 16 + l15;
          const int cb = (ks * 64 + g * 16) ^ ((r & 7) << 4);
          const bf16x8 kf = *reinterpret_cast<const bf16x8*>(Kbuf + r * 128 + (cb >> 1));
          s[st * 4 + nf2] = __builtin_amdgcn_mfma_f32_16x16x32_bf16(qf[ks], kf, s[st * 4 + nf2], 0, 0, 0);
        }
      }
      __builtin_amdgcn_s_setprio(0);
      __builtin_amdgcn_sched_barrier(0);
      ENDPHASE(p);
    }
    float mv[4];
    #pragma unroll
    for (int r = 0; r < 4; ++r) {
      float m0v = s[0][r];
      #pragma unroll
      for (int nf = 1; nf < 16; ++nf) m0v = fmaxf(m0v, s[nf][r]);
      m0v = fmaxf(m0v, __shfl_xor(m0v, 1));
      m0v = fmaxf(m0v, __shfl_xor(m0v, 2));
      m0v = fmaxf(m0v, __shfl_xor(m0v, 4));
      m0v = fmaxf(m0v, __shfl_xor(m0v, 8));
      mv[r] = m0v;
    }
    #pragma unroll
    for (int r = 0; r < 4; ++r) {
      float ds = 0.f;
      #pragma unroll
      for (int nf = 0; nf < 16; ++nf) {
        const float e = exp2f((s[nf][r] - mv[r]) * SC);
        s[nf][r] = e;
        ds += e;
      }
      den[r] += ds;
    }
    #pragma unroll
    for (int h2 = 0; h2 < 2; ++h2) {
      #pragma unroll
      for (int nf = 0; nf < 8; ++nf)
        #pragma unroll
        for (int r = 0; r < 4; ++r)
          E[w][4 * g + r][nf * 16 + l15] = (__bf16)s[h2 * 8 + nf][r];
      #pragma unroll
      for (int sv = 0; sv < 2; ++sv) {
        const int p = pb + 4 + h2 * 2 + sv;
        if (p + 2 < 32) STAGE(p + 2);
        const __bf16* Vbuf = U[p % 3];
        __builtin_amdgcn_s_setprio(1);
        #pragma unroll
        for (int ks2 = 0; ks2 < 2; ++ks2) {
          const bf16x8 a = *reinterpret_cast<const bf16x8*>(
              &E[w][l15][sv * 64 + ks2 * 32 + 8 * g]);
          #pragma unroll
          for (int nd = 0; nd < 8; ++nd) {
            const int d = nd * 16 + l15;
            const int cb = (ks2 * 64 + g * 16) ^ ((d & 7) << 4);
            const bf16x8 vf = *reinterpret_cast<const bf16x8*>(Vbuf + d * 64 + (cb >> 1));
            num[nd] = __builtin_amdgcn_mfma_f32_16x16x32_bf16(a, vf, num[nd], 0, 0, 0);
          }
        }
        __builtin_amdgcn_s_setprio(0);
        __builtin_amdgcn_sched_barrier(0);
        ENDPHASE(p);
      }
    }
  }

  #pragma unroll
  for (int r = 0; r < 4; ++r) {
    den[r] += __shfl_xor(den[r], 1);
    den[r] += __shfl_xor(den[r], 2);
    den[r] += __shfl_xor(den[r], 4);
    den[r] += __shfl_xor(den[r], 8);
    den[r] += 1e-8f;
  }

  #pragma unroll
  for (int nd = 0; nd < 8; ++nd)
    #pragma unroll
    for (int r = 0; r < 4; ++r) {
      const int sq = q0 + 4 * g + r;
      const int srow = 2 * sq + pp;
      const int m = b * 2048 + srow;
      const int k = h * 128 + nd * 16 + l15;
      const size_t dst = ((size_t)(k >> 5) * 32 + (m >> 7)) * 4096 +
                         (size_t)((k >> 3) & 3) * 1024 + (m & 127) * 8 + (k & 7);
      attnA[dst] = (__bf16)(num[nd][r] / den[r]);
    }
}

extern "C" void kernel_launch(void* const* d_in, const int* in_sizes, int n_in,
                              void* d_out, int out_size, void* d_ws, size_t ws_size,
                              hipStream_t stream) {
  (void)in_sizes; (void)n_in; (void)out_size; (void)ws_size;
  const float* x    = (const float*)d_in[0];
  const float* wqkv = (const float*)d_in[1];
  const float* wout = (const float*)d_in[2];
  float* out = (float*)d_out;
  uint8_t* ws = (uint8_t*)d_ws;

  // workspace layout (bytes); total needed = 96 MB
  __bf16* xbf   = (__bf16*)(ws + 0);                    // 16 MB blocked A (GEMM1)
  __bf16* wqkvt = (__bf16*)(ws + (16ull << 20));        // 24 MB blocked B (GEMM1, RB=48)
  __bf16* woutt = (__bf16*)(ws + (40ull << 20));        //  8 MB blocked B (GEMM2, RB=16)
  __bf16* Qp    = (__bf16*)(ws + (48ull << 20));        // 16 MB [b][h][p][1024][128]
  __bf16* Kp    = (__bf16*)(ws + (64ull << 20));        // 16 MB [b][h][p][1024][128]
  __bf16* Vt    = (__bf16*)(ws + (80ull << 20));        // 16 MB [b][h][p][128][1024]
  __bf16* attnA = (__bf16*)(ws + 0);                    // 16 MB blocked A (GEMM2); reuse xbf

  // fused conversions: x-blk (4096) + wqkv-blk (3072) + wout-blk (1024)
  k_cvt_all<<<8192, 256, 0, stream>>>(x, xbf, wqkv, wqkvt, wout, woutt);
  // qkv projection: r18-best (r8 loop, nb-strip 6/XCD)
  k_gemm_r8<48, 192, 6, 1><<<1536, 256, 0, stream>>>(xbf, wqkvt, Qp, Kp, Vt, nullptr);
  // fused dilated attention v5 (r8-pipelined; writes blocked A for GEMM2)
  k_attn<<<1024, 256, 0, stream>>>(Qp, Kp, Vt, attnA);
  // output projection: r8 loop, nb-strip 2/XCD (1MB B-strip L2-resident)
  k_gemm_r8<16, 64, 2, 2><<<512, 256, 0, stream>>>(attnA, woutt, nullptr, nullptr, nullptr, out);
}